// Round 3
// baseline (1422.067 us; speedup 1.0000x reference)
//
#include <hip/hip_runtime.h>

// Problem dims (fixed)
#define BB   4
#define LQ   1024
#define LK   2048
#define D1   1024
#define D2   1280

// ---------------------------------------------------------------------------
// Generic strided-batched fp32 GEMM:
//   C[bz][m][n] = scale * sum_k A[bz][m][k] * Bsel(bz,k,n)  (+ bias[n])
//   BT=true : Bsel = B[bz][n*ldb + k]   (B stored [N][K], i.e. x @ W^T)
//   BT=false: Bsel = B[bz][k*ldb + n]   (B stored [K][N])
// 64x64 block tile, 256 threads, 4x4 micro-tile per thread, K-tile 16.
// All dims are multiples of tile sizes (no bounds checks). Strides in elems.
// ---------------------------------------------------------------------------
template <bool BT>
__global__ __launch_bounds__(256) void gemm_kernel(
    const float* __restrict__ A, const float* __restrict__ Bm,
    float* __restrict__ C, const float* __restrict__ bias,
    int M, int N, int Kd, int lda, int ldb, int ldc,
    long strideA, long strideB, long strideC, float scale)
{
    __shared__ float As[16][64];   // [k][m]
    __shared__ float Bs[16][64];   // [k][n]

    const int bz = blockIdx.z;
    const float* Ab = A + (long)bz * strideA;
    const float* Bb = Bm + (long)bz * strideB;

    const int m0 = blockIdx.y * 64;
    const int n0 = blockIdx.x * 64;
    const int t  = threadIdx.x;          // 0..255
    const int tx = t & 15;               // n micro-tile
    const int ty = t >> 4;               // m micro-tile

    float acc[4][4] = {};

    for (int k0 = 0; k0 < Kd; k0 += 16) {
        // --- stage A tile (64 m x 16 k) -> As[k][m]
        {
            const int r  = t >> 2;            // 0..63 (m)
            const int kc = (t & 3) * 4;       // 0,4,8,12 (k)
            const float4 av = *(const float4*)(Ab + (long)(m0 + r) * lda + k0 + kc);
            As[kc + 0][r] = av.x;
            As[kc + 1][r] = av.y;
            As[kc + 2][r] = av.z;
            As[kc + 3][r] = av.w;
        }
        // --- stage B tile -> Bs[k][n]
        if (BT) {
            const int r  = t >> 2;            // 0..63 (n)
            const int kc = (t & 3) * 4;       // k
            const float4 bv = *(const float4*)(Bb + (long)(n0 + r) * ldb + k0 + kc);
            Bs[kc + 0][r] = bv.x;
            Bs[kc + 1][r] = bv.y;
            Bs[kc + 2][r] = bv.z;
            Bs[kc + 3][r] = bv.w;
        } else {
            const int kr = t >> 4;            // 0..15 (k)
            const int c  = (t & 15) * 4;      // 0..60 (n)
            const float4 bv = *(const float4*)(Bb + (long)(k0 + kr) * ldb + n0 + c);
            *(float4*)&Bs[kr][c] = bv;
        }
        __syncthreads();

        #pragma unroll
        for (int kk = 0; kk < 16; ++kk) {
            const float4 av = *(const float4*)&As[kk][ty * 4];
            const float4 bv = *(const float4*)&Bs[kk][tx * 4];
            acc[0][0] += av.x * bv.x; acc[0][1] += av.x * bv.y;
            acc[0][2] += av.x * bv.z; acc[0][3] += av.x * bv.w;
            acc[1][0] += av.y * bv.x; acc[1][1] += av.y * bv.y;
            acc[1][2] += av.y * bv.z; acc[1][3] += av.y * bv.w;
            acc[2][0] += av.z * bv.x; acc[2][1] += av.z * bv.y;
            acc[2][2] += av.z * bv.z; acc[2][3] += av.z * bv.w;
            acc[3][0] += av.w * bv.x; acc[3][1] += av.w * bv.y;
            acc[3][2] += av.w * bv.z; acc[3][3] += av.w * bv.w;
        }
        __syncthreads();
    }

    // --- epilogue (fp32 output)
    const long cbase = (long)bz * strideC;
    #pragma unroll
    for (int i = 0; i < 4; ++i) {
        const int m = m0 + ty * 4 + i;
        #pragma unroll
        for (int j = 0; j < 4; ++j) {
            const int n = n0 + tx * 4 + j;
            float v = acc[i][j] * scale;
            if (bias) v += bias[n];
            C[cbase + (long)m * ldc + n] = v;
        }
    }
}

// ---------------------------------------------------------------------------
// Row softmax over LK=2048 columns, one block (256 threads) per row, in-place.
// ---------------------------------------------------------------------------
__global__ __launch_bounds__(256) void softmax_kernel(float* __restrict__ S)
{
    const long row = blockIdx.x;             // 0 .. BB*LQ-1
    float* p = S + row * LK;
    const int t = threadIdx.x;

    float r[8];
    float mx = -1e30f;
    #pragma unroll
    for (int i = 0; i < 8; ++i) {
        r[i] = p[t + i * 256];
        mx = fmaxf(mx, r[i]);
    }

    __shared__ float red[256];
    red[t] = mx;
    __syncthreads();
    for (int s = 128; s > 0; s >>= 1) {
        if (t < s) red[t] = fmaxf(red[t], red[t + s]);
        __syncthreads();
    }
    mx = red[0];
    __syncthreads();

    float sum = 0.f;
    #pragma unroll
    for (int i = 0; i < 8; ++i) {
        r[i] = __expf(r[i] - mx);
        sum += r[i];
    }
    red[t] = sum;
    __syncthreads();
    for (int s = 128; s > 0; s >>= 1) {
        if (t < s) red[t] += red[t + s];
        __syncthreads();
    }
    const float inv = 1.0f / red[0];

    #pragma unroll
    for (int i = 0; i < 8; ++i)
        p[t + i * 256] = r[i] * inv;
}

// ---------------------------------------------------------------------------
extern "C" void kernel_launch(void* const* d_in, const int* in_sizes, int n_in,
                              void* d_out, int out_size, void* d_ws, size_t ws_size,
                              hipStream_t stream)
{
    // Inputs are fp32 (reference dtypes). Output is fp32.
    const float* Q  = (const float*)d_in[0];
    const float* K  = (const float*)d_in[1];
    const float* V  = (const float*)d_in[2];
    const float* Wk = (const float*)d_in[3];
    const float* bk = (const float*)d_in[4];
    const float* Wv = (const float*)d_in[5];
    const float* bv = (const float*)d_in[6];
    const float* Wo = (const float*)d_in[7];
    const float* bo = (const float*)d_in[8];
    float* out = (float*)d_out;

    // Workspace (fp32): Kp | Vp | S ; Ctx aliases Kp (dead after scores).
    // Total: 3 * 33.6 MB = 100.6 MB.
    float* Kp  = (float*)d_ws;                       // [BB*LK, D1]
    float* Vp  = Kp + (long)BB * LK * D1;            // [BB*LK, D1]
    float* S   = Vp + (long)BB * LK * D1;            // [BB, LQ, LK]
    float* Ctx = Kp;                                 // [BB, LQ, D1] (alias)

    const float inv_sqrt_d = 0.03125f;               // 1/sqrt(1024)

    // 1) K_proj = K @ Wk^T + bk   ([8192,1280] x [1024,1280]^T)
    gemm_kernel<true><<<dim3(D1 / 64, (BB * LK) / 64, 1), 256, 0, stream>>>(
        K, Wk, Kp, bk, BB * LK, D1, D2, D2, D2, D1, 0, 0, 0, 1.0f);

    // 2) V_proj = V @ Wv^T + bv
    gemm_kernel<true><<<dim3(D1 / 64, (BB * LK) / 64, 1), 256, 0, stream>>>(
        V, Wv, Vp, bv, BB * LK, D1, D2, D2, D2, D1, 0, 0, 0, 1.0f);

    // 3) scores = Q @ K_proj^T * (1/32)   per batch
    gemm_kernel<true><<<dim3(LK / 64, LQ / 64, BB), 256, 0, stream>>>(
        Q, Kp, S, nullptr, LQ, LK, D1, D1, D1, LK,
        (long)LQ * D1, (long)LK * D1, (long)LQ * LK, inv_sqrt_d);

    // 4) softmax rows (in place)
    softmax_kernel<<<dim3(BB * LQ, 1, 1), 256, 0, stream>>>(S);

    // 5) context = probs @ V_proj   per batch (B is [K][N])
    gemm_kernel<false><<<dim3(D1 / 64, LQ / 64, BB), 256, 0, stream>>>(
        S, Vp, Ctx, nullptr, LQ, D1, LK, LK, D1, D1,
        (long)LQ * LK, (long)LK * D1, (long)LQ * D1, 1.0f);

    // 6) out = context @ Wo^T + bo  (batch folded into M) -> fp32
    gemm_kernel<true><<<dim3(D1 / 64, (BB * LQ) / 64, 1), 256, 0, stream>>>(
        Ctx, Wo, out, bo, BB * LQ, D1, D1, D1, D1, D1, 0, 0, 0, 1.0f);
}

// Round 4
// 365.535 us; speedup vs baseline: 3.8904x; 3.8904x over previous
//
#include <hip/hip_runtime.h>

// Problem dims (fixed)
#define BB   4
#define LQ   1024
#define LK   2048
#define D1   1024
#define D2   1280

typedef unsigned short u16;
typedef __attribute__((ext_vector_type(8))) short   short8;   // 8 bf16 = 4 VGPRs
typedef __attribute__((ext_vector_type(4))) float   floatx4;  // MFMA accum

__device__ __forceinline__ u16 f2bf(float f) {
    unsigned u = __float_as_uint(f);
    unsigned r = (u + 0x7FFFu + ((u >> 16) & 1u)) >> 16;   // RNE
    return (u16)r;
}

// async global->LDS, 16B per lane; LDS dest = wave-uniform base + lane*16
__device__ __forceinline__ void gl_lds16(const void* g, void* l) {
    __builtin_amdgcn_global_load_lds(
        (const __attribute__((address_space(1))) unsigned int*)g,
        (__attribute__((address_space(3))) unsigned int*)l, 16, 0, 0);
}

// fp32 -> bf16 elementwise cast (n % 4 == 0)
__global__ __launch_bounds__(256) void cast_kernel(
    const float* __restrict__ in, u16* __restrict__ out, long n)
{
    long i = ((long)blockIdx.x * 256 + threadIdx.x) * 4;
    if (i >= n) return;
    const float4 v = *(const float4*)(in + i);
    ushort4 o;
    o.x = f2bf(v.x); o.y = f2bf(v.y); o.z = f2bf(v.z); o.w = f2bf(v.w);
    *(ushort4*)(out + i) = o;
}

// ---------------------------------------------------------------------------
// bf16 MFMA GEMM, both operands in [rows][K] layout (B is N x K, i.e. x@W^T):
//   C[bz][m][n] = epi( sum_k A[bz][m][k] * B[bz][n][k] )
// 128x128 tile, BK=32, 256 threads = 4 waves (2x2 of 64x64), 16x16x32 MFMA.
// All dims multiples of 128 (M,N) / 32 (K). Strides in elements.
// ---------------------------------------------------------------------------
enum { EPI_F32_SCALE, EPI_F32_BIAS, EPI_BF16_BIAS, EPI_BF16, EPI_BF16_T_BIAS };

template <int EPI>
__global__ __launch_bounds__(256) void mm_bf16(
    const u16* __restrict__ A, const u16* __restrict__ B,
    void* __restrict__ C, const float* __restrict__ bias,
    int Kd, int lda, int ldb, int ldc,
    long sA, long sB, long sC, float scale)
{
    __shared__ u16 As[128 * 32];   // [m][k], 32 k per row (64B)
    __shared__ u16 Bs[128 * 32];   // [n][k]

    const int bz = blockIdx.z;
    const u16* Ab = A + (long)bz * sA + (long)blockIdx.y * 128 * lda;
    const u16* Bb = B + (long)bz * sB + (long)blockIdx.x * 128 * ldb;

    const int t    = threadIdx.x;
    const int w    = t >> 6;          // wave 0..3
    const int l    = t & 63;
    const int l16  = l & 15;
    const int quad = l >> 4;
    const int wm   = (w >> 1) * 64;   // wave tile origin in block
    const int wn   = (w & 1) * 64;

    floatx4 acc[4][4];
    #pragma unroll
    for (int i = 0; i < 4; ++i)
        #pragma unroll
        for (int j = 0; j < 4; ++j)
            acc[i][j] = (floatx4){0.f, 0.f, 0.f, 0.f};

    for (int k0 = 0; k0 < Kd; k0 += 32) {
        // stage 128x32 bf16 A and B tiles (8KB each) via global_load_lds
        #pragma unroll
        for (int c = 0; c < 2; ++c) {
            const int idx = w * 128 + c * 64 + l;   // 0..511
            const int mr  = idx >> 2;               // row in tile
            const int kq  = idx & 3;                // 8-elem k-quad
            gl_lds16(Ab + (long)mr * lda + k0 + kq * 8, (char*)As + (w * 2 + c) * 1024);
            gl_lds16(Bb + (long)mr * ldb + k0 + kq * 8, (char*)Bs + (w * 2 + c) * 1024);
        }
        __syncthreads();   // compiler emits vmcnt(0) drain before s_barrier

        short8 af[4], bfr[4];
        #pragma unroll
        for (int i = 0; i < 4; ++i) {
            af[i]  = *(const short8*)(As + (wm + i * 16 + l16) * 32 + quad * 8);
            bfr[i] = *(const short8*)(Bs + (wn + i * 16 + l16) * 32 + quad * 8);
        }
        #pragma unroll
        for (int i = 0; i < 4; ++i)
            #pragma unroll
            for (int j = 0; j < 4; ++j)
                acc[i][j] = __builtin_amdgcn_mfma_f32_16x16x32_bf16(
                    af[i], bfr[j], acc[i][j], 0, 0, 0);
        __syncthreads();
    }

    // epilogue: C/D layout col = lane&15, row = quad*4 + reg
    const long cb = (long)bz * sC;
    const int  mb = blockIdx.y * 128 + wm;
    const int  nb = blockIdx.x * 128 + wn;
    #pragma unroll
    for (int i = 0; i < 4; ++i) {
        #pragma unroll
        for (int j = 0; j < 4; ++j) {
            const int col  = nb + j * 16 + l16;
            const int row0 = mb + i * 16 + quad * 4;
            const floatx4 v = acc[i][j];
            if (EPI == EPI_F32_SCALE) {
                float* Cp = (float*)C;
                #pragma unroll
                for (int r = 0; r < 4; ++r)
                    Cp[cb + (long)(row0 + r) * ldc + col] = v[r] * scale;
            } else if (EPI == EPI_F32_BIAS) {
                float* Cp = (float*)C;
                const float bs = bias[col];
                #pragma unroll
                for (int r = 0; r < 4; ++r)
                    Cp[cb + (long)(row0 + r) * ldc + col] = v[r] + bs;
            } else if (EPI == EPI_BF16_BIAS) {
                u16* Cp = (u16*)C;
                const float bs = bias[col];
                #pragma unroll
                for (int r = 0; r < 4; ++r)
                    Cp[cb + (long)(row0 + r) * ldc + col] = f2bf(v[r] + bs);
            } else if (EPI == EPI_BF16) {
                u16* Cp = (u16*)C;
                #pragma unroll
                for (int r = 0; r < 4; ++r)
                    Cp[cb + (long)(row0 + r) * ldc + col] = f2bf(v[r]);
            } else { // EPI_BF16_T_BIAS: store C^T[col][row0..row0+3], bias on col
                u16* Cp = (u16*)C;
                const float bs = bias[col];
                ushort4 pk;
                pk.x = f2bf(v[0] + bs); pk.y = f2bf(v[1] + bs);
                pk.z = f2bf(v[2] + bs); pk.w = f2bf(v[3] + bs);
                *(ushort4*)(Cp + cb + (long)col * ldc + row0) = pk;
            }
        }
    }
}

// ---------------------------------------------------------------------------
// Row softmax: read fp32 S row (2048), write bf16 P row. One block per row.
// ---------------------------------------------------------------------------
__global__ __launch_bounds__(256) void softmax_kernel(
    const float* __restrict__ S, u16* __restrict__ P)
{
    const long row = blockIdx.x;             // 0 .. BB*LQ-1
    const float* p = S + row * LK;
    u16* q = P + row * LK;
    const int t = threadIdx.x;

    float r[8];
    float mx = -1e30f;
    #pragma unroll
    for (int i = 0; i < 8; ++i) {
        r[i] = p[t + i * 256];
        mx = fmaxf(mx, r[i]);
    }

    __shared__ float red[256];
    red[t] = mx;
    __syncthreads();
    for (int s = 128; s > 0; s >>= 1) {
        if (t < s) red[t] = fmaxf(red[t], red[t + s]);
        __syncthreads();
    }
    mx = red[0];
    __syncthreads();

    float sum = 0.f;
    #pragma unroll
    for (int i = 0; i < 8; ++i) {
        r[i] = __expf(r[i] - mx);
        sum += r[i];
    }
    red[t] = sum;
    __syncthreads();
    for (int s = 128; s > 0; s >>= 1) {
        if (t < s) red[t] += red[t + s];
        __syncthreads();
    }
    const float inv = 1.0f / red[0];

    #pragma unroll
    for (int i = 0; i < 8; ++i)
        q[t + i * 256] = f2bf(r[i] * inv);
}

// ---------------------------------------------------------------------------
extern "C" void kernel_launch(void* const* d_in, const int* in_sizes, int n_in,
                              void* d_out, int out_size, void* d_ws, size_t ws_size,
                              hipStream_t stream)
{
    const float* Q  = (const float*)d_in[0];
    const float* K  = (const float*)d_in[1];
    const float* V  = (const float*)d_in[2];
    const float* Wk = (const float*)d_in[3];
    const float* bk = (const float*)d_in[4];
    const float* Wv = (const float*)d_in[5];
    const float* bv = (const float*)d_in[6];
    const float* Wo = (const float*)d_in[7];
    const float* bo = (const float*)d_in[8];
    float* out = (float*)d_out;

    // Workspace layout (bytes), total 90.7 MB (<=118 MB proven available):
    //   bufA  [0, 21.0MB)  : Kbf -> Vbf -> Qbf -> P (lifetimes disjoint)
    //   bufW  [21.0, 23.6) : Wkbf -> Wvbf -> Wobf
    //   Kp    [23.6, 40.4) : bf16 K_proj;  Ctx aliases it after scores GEMM
    //   VpT   [40.4, 57.1) : bf16 V_proj transposed [b][d][k]
    //   S     [57.1, 90.7) : fp32 scores
    char* ws = (char*)d_ws;
    u16*   bufA = (u16*)(ws);
    u16*   bufW = (u16*)(ws + 20971520);
    u16*   Kp   = (u16*)(ws + 23592960);
    u16*   VpT  = (u16*)(ws + 40370176);
    float* S    = (float*)(ws + 57147392);
    u16*   Ctx  = Kp;      // alias (Kp dead after scores GEMM)
    u16*   P    = bufA;    // alias (Qbf dead after scores GEMM)

    const float inv_sqrt_d = 0.03125f;   // 1/sqrt(1024)

    // ---- K projection: Kp[b][k][d] = K @ Wk^T + bk
    cast_kernel<<<dim3((BB*LK*D2/4 + 255)/256), 256, 0, stream>>>(K, bufA, (long)BB*LK*D2);
    cast_kernel<<<dim3((D1*D2/4 + 255)/256),   256, 0, stream>>>(Wk, bufW, (long)D1*D2);
    mm_bf16<EPI_BF16_BIAS><<<dim3(D1/128, LK/128, BB), 256, 0, stream>>>(
        bufA, bufW, Kp, bk, D2, D2, D2, D1,
        (long)LK*D2, 0, (long)LK*D1, 1.0f);

    // ---- V projection (transposed out): VpT[b][d][k] = (V @ Wv^T + bv)^T
    cast_kernel<<<dim3((BB*LK*D2/4 + 255)/256), 256, 0, stream>>>(V, bufA, (long)BB*LK*D2);
    cast_kernel<<<dim3((D1*D2/4 + 255)/256),   256, 0, stream>>>(Wv, bufW, (long)D1*D2);
    mm_bf16<EPI_BF16_T_BIAS><<<dim3(D1/128, LK/128, BB), 256, 0, stream>>>(
        bufA, bufW, VpT, bv, D2, D2, D2, LK,
        (long)LK*D2, 0, (long)D1*LK, 1.0f);

    // ---- scores: S[b][q][k] = (Q @ Kp^T) / 32   (fp32 out)
    cast_kernel<<<dim3((BB*LQ*D1/4 + 255)/256), 256, 0, stream>>>(Q, bufA, (long)BB*LQ*D1);
    mm_bf16<EPI_F32_SCALE><<<dim3(LK/128, LQ/128, BB), 256, 0, stream>>>(
        bufA, Kp, S, nullptr, D1, D1, D1, LK,
        (long)LQ*D1, (long)LK*D1, (long)LQ*LK, inv_sqrt_d);

    // ---- softmax rows -> bf16 probs P
    softmax_kernel<<<dim3(BB*LQ), 256, 0, stream>>>(S, P);

    // ---- context: Ctx[b][q][d] = P @ VpT^T  (B operand is VpT [d][k] = N x K)
    mm_bf16<EPI_BF16><<<dim3(D1/128, LQ/128, BB), 256, 0, stream>>>(
        P, VpT, Ctx, nullptr, LK, LK, LK, D1,
        (long)LQ*LK, (long)D1*LK, (long)LQ*D1, 1.0f);

    // ---- output: out = Ctx @ Wo^T + bo  (fp32, batch folded into M)
    cast_kernel<<<dim3((D1*D1/4 + 255)/256), 256, 0, stream>>>(Wo, bufW, (long)D1*D1);
    mm_bf16<EPI_F32_BIAS><<<dim3(D1/128, (BB*LQ)/128, 1), 256, 0, stream>>>(
        Ctx, bufW, out, bo, D1, D1, D1, D1,
        0, 0, 0, 1.0f);
}

// Round 7
// 320.072 us; speedup vs baseline: 4.4430x; 1.1420x over previous
//
#include <hip/hip_runtime.h>

// Problem dims (fixed)
#define BB   4
#define LQ   1024
#define LK   2048
#define D1   1024
#define D2   1280

typedef unsigned short u16;
typedef __attribute__((ext_vector_type(8))) short   short8;   // 8 bf16 = 4 VGPRs
typedef __attribute__((ext_vector_type(4))) float   floatx4;  // MFMA accum

__device__ __forceinline__ u16 f2bf(float f) {
    unsigned u = __float_as_uint(f);
    unsigned r = (u + 0x7FFFu + ((u >> 16) & 1u)) >> 16;   // RNE
    return (u16)r;
}

// async global->LDS, 16B per lane; LDS dest = wave-uniform base + lane*16
__device__ __forceinline__ void gl_lds16(const void* g, void* l) {
    __builtin_amdgcn_global_load_lds(
        (const __attribute__((address_space(1))) unsigned int*)g,
        (__attribute__((address_space(3))) unsigned int*)l, 16, 0, 0);
}

// ---------------------------------------------------------------------------
// Batched fp32 -> bf16 cast: 6 tensors in ONE launch.
// ---------------------------------------------------------------------------
struct CastDesc {
    const float* src[6];
    u16*         dst[6];
    long         end[6];      // cumulative end in QUADS (4 elems)
};

__global__ __launch_bounds__(256) void cast6_kernel(CastDesc d, long total_quads)
{
    long gi = (long)blockIdx.x * 256 + threadIdx.x;
    if (gi >= total_quads) return;
    int s = 0;
    while (gi >= d.end[s]) ++s;            // 6 segments, short loop
    const long start = (s == 0) ? 0 : d.end[s - 1];
    const long q = gi - start;
    const float4 v = *(const float4*)(d.src[s] + q * 4);
    ushort4 o;
    o.x = f2bf(v.x); o.y = f2bf(v.y); o.z = f2bf(v.z); o.w = f2bf(v.w);
    *(ushort4*)(d.dst[s] + q * 4) = o;
}

// ---------------------------------------------------------------------------
// bf16 MFMA GEMM, operands in [rows][K] layout (B is N x K, i.e. x @ W^T):
//   C[bz][m][n] = epi( sum_k A[bz][m][k] * B[bz][n][k] )
// 128 x BN tile (BN=128 or 64), BK=64, 256 threads = 4 waves (2x2), 16x16x32
// MFMA, global_load_lds(16B) staging. Dims: M%128==0, N%BN==0, K%64==0.
// NOTE: EPI_BF16_T_BIAS requires M == ldc per batch -> MUST be z-batched,
// never batch-folded into M (R5/R6 bug: folded rows smear across batches).
// ---------------------------------------------------------------------------
enum { EPI_F32_SCALE, EPI_F32_BIAS, EPI_BF16_BIAS, EPI_BF16, EPI_BF16_T_BIAS };

template <int BN, int EPI>
__global__ __launch_bounds__(256, 2) void mm_bf16(
    const u16* __restrict__ A, const u16* __restrict__ B,
    void* __restrict__ C, const float* __restrict__ bias,
    int Kd, int lda, int ldb, int ldc,
    long sA, long sB, long sC, float scale)
{
    constexpr int NJ  = BN / 32;     // j-fragments per wave (4 or 2)
    constexpr int NBI = BN / 32;     // B staging issues per wave (4 or 2)

    __shared__ u16 As[128 * 64];     // [m][k], 64 k per row (128B) = 16 KB
    __shared__ u16 Bs[BN * 64];      // [n][k]                      = 16/8 KB

    const int bz = blockIdx.z;
    const u16* Ab = A + (long)bz * sA + (long)blockIdx.y * 128 * lda;
    const u16* Bb = B + (long)bz * sB + (long)blockIdx.x * BN  * ldb;

    const int t    = threadIdx.x;
    const int w    = t >> 6;              // wave 0..3
    const int l    = t & 63;
    const int l16  = l & 15;
    const int quad = l >> 4;
    const int wm   = (w >> 1) * 64;       // wave origin in block tile
    const int wn   = (w & 1) * (BN / 2);

    floatx4 acc[4][NJ];
    #pragma unroll
    for (int i = 0; i < 4; ++i)
        #pragma unroll
        for (int j = 0; j < NJ; ++j)
            acc[i][j] = (floatx4){0.f, 0.f, 0.f, 0.f};

    for (int k0 = 0; k0 < Kd; k0 += 64) {
        // ---- stage A (128x64 = 16KB) and B (BNx64) tiles
        #pragma unroll
        for (int c = 0; c < 4; ++c) {
            const int idx = (w * 4 + c) * 64 + l;    // 0..1023
            const int mr  = idx >> 3;                // row
            const int kq  = idx & 7;                 // 16B chunk in row
            gl_lds16(Ab + (long)mr * lda + k0 + kq * 8, (char*)As + (w * 4 + c) * 1024);
        }
        #pragma unroll
        for (int c = 0; c < NBI; ++c) {
            const int idx = (w * NBI + c) * 64 + l;
            const int mr  = idx >> 3;
            const int kq  = idx & 7;
            gl_lds16(Bb + (long)mr * ldb + k0 + kq * 8, (char*)Bs + (w * NBI + c) * 1024);
        }
        __syncthreads();

        // ---- 2 x K=32 MFMA steps per staged tile
        #pragma unroll
        for (int q = 0; q < 2; ++q) {
            short8 af[4], bfr[NJ];
            #pragma unroll
            for (int i = 0; i < 4; ++i)
                af[i]  = *(const short8*)(As + (wm + i * 16 + l16) * 64 + q * 32 + quad * 8);
            #pragma unroll
            for (int j = 0; j < NJ; ++j)
                bfr[j] = *(const short8*)(Bs + (wn + j * 16 + l16) * 64 + q * 32 + quad * 8);
            #pragma unroll
            for (int i = 0; i < 4; ++i)
                #pragma unroll
                for (int j = 0; j < NJ; ++j)
                    acc[i][j] = __builtin_amdgcn_mfma_f32_16x16x32_bf16(
                        af[i], bfr[j], acc[i][j], 0, 0, 0);
        }
        __syncthreads();
    }

    // ---- epilogue: C/D layout col = lane&15, row = quad*4 + reg
    const long cb = (long)bz * sC;
    const int  mb = blockIdx.y * 128 + wm;
    const int  nb = blockIdx.x * BN  + wn;
    #pragma unroll
    for (int i = 0; i < 4; ++i) {
        #pragma unroll
        for (int j = 0; j < NJ; ++j) {
            const int col  = nb + j * 16 + l16;
            const int row0 = mb + i * 16 + quad * 4;
            const floatx4 v = acc[i][j];
            if (EPI == EPI_F32_SCALE) {
                float* Cp = (float*)C;
                #pragma unroll
                for (int r = 0; r < 4; ++r)
                    Cp[cb + (long)(row0 + r) * ldc + col] = v[r] * scale;
            } else if (EPI == EPI_F32_BIAS) {
                float* Cp = (float*)C;
                const float bs = bias[col];
                #pragma unroll
                for (int r = 0; r < 4; ++r)
                    Cp[cb + (long)(row0 + r) * ldc + col] = v[r] + bs;
            } else if (EPI == EPI_BF16_BIAS) {
                u16* Cp = (u16*)C;
                const float bs = bias[col];
                #pragma unroll
                for (int r = 0; r < 4; ++r)
                    Cp[cb + (long)(row0 + r) * ldc + col] = f2bf(v[r] + bs);
            } else if (EPI == EPI_BF16) {
                u16* Cp = (u16*)C;
                #pragma unroll
                for (int r = 0; r < 4; ++r)
                    Cp[cb + (long)(row0 + r) * ldc + col] = f2bf(v[r]);
            } else { // EPI_BF16_T_BIAS: store C^T[col][row0..+3], bias on col
                u16* Cp = (u16*)C;
                const float bs = bias[col];
                ushort4 pk;
                pk.x = f2bf(v[0] + bs); pk.y = f2bf(v[1] + bs);
                pk.z = f2bf(v[2] + bs); pk.w = f2bf(v[3] + bs);
                *(ushort4*)(Cp + cb + (long)col * ldc + row0) = pk;
            }
        }
    }
}

// ---------------------------------------------------------------------------
// Row softmax: read fp32 S row (2048), write bf16 P row. One block per row.
// ---------------------------------------------------------------------------
__global__ __launch_bounds__(256) void softmax_kernel(
    const float* __restrict__ S, u16* __restrict__ P)
{
    const long row = blockIdx.x;
    const float* p = S + row * LK;
    u16* q = P + row * LK;
    const int t = threadIdx.x;

    float r[8];
    float mx = -1e30f;
    #pragma unroll
    for (int i = 0; i < 8; ++i) {
        r[i] = p[t + i * 256];
        mx = fmaxf(mx, r[i]);
    }

    __shared__ float red[256];
    red[t] = mx;
    __syncthreads();
    for (int s = 128; s > 0; s >>= 1) {
        if (t < s) red[t] = fmaxf(red[t], red[t + s]);
        __syncthreads();
    }
    mx = red[0];
    __syncthreads();

    float sum = 0.f;
    #pragma unroll
    for (int i = 0; i < 8; ++i) {
        r[i] = __expf(r[i] - mx);
        sum += r[i];
    }
    red[t] = sum;
    __syncthreads();
    for (int s = 128; s > 0; s >>= 1) {
        if (t < s) red[t] += red[t + s];
        __syncthreads();
    }
    const float inv = 1.0f / red[0];

    #pragma unroll
    for (int i = 0; i < 8; ++i)
        q[t + i * 256] = f2bf(r[i] * inv);
}

// ---------------------------------------------------------------------------
extern "C" void kernel_launch(void* const* d_in, const int* in_sizes, int n_in,
                              void* d_out, int out_size, void* d_ws, size_t ws_size,
                              hipStream_t stream)
{
    const float* Q  = (const float*)d_in[0];
    const float* K  = (const float*)d_in[1];
    const float* V  = (const float*)d_in[2];
    const float* Wk = (const float*)d_in[3];
    const float* bk = (const float*)d_in[4];
    const float* Wv = (const float*)d_in[5];
    const float* bv = (const float*)d_in[6];
    const float* Wo = (const float*)d_in[7];
    const float* bo = (const float*)d_in[8];
    float* out = (float*)d_out;

    // Workspace layout (max extent 94.4 MB <= 100.6 MB proven):
    //   Kbf  [0.0, 21.0)M   dead after Kproj GEMM
    //   Vbf  [22.0, 43.0)M  dead after Vproj GEMM
    //   Qbf  [44.0, 52.4)M  dead after scores GEMM
    //   Wkbf [52.8, 55.4)M  Wvbf [55.6, 58.2)M  Wobf [58.3, 60.4)M
    //   Kp   [60.8, 77.6)M  bf16 K_proj; Ctx aliases it after scores
    //   VpT  [77.6, 94.4)M  bf16 V_proj^T [b][d][k]
    //   S    [0.0, 33.6)M   fp32 scores  (aliases dead Kbf + Vbf head)
    //   P    [35.3, 52.0)M  bf16 probs   (aliases dead Vbf tail + Qbf)
    char* ws = (char*)d_ws;
    u16*   Kbf  = (u16*)(ws);
    u16*   Vbf  = (u16*)(ws + 22020096);
    u16*   Qbf  = (u16*)(ws + 44040192);
    u16*   Wkbf = (u16*)(ws + 52828160);
    u16*   Wvbf = (u16*)(ws + 55574528);
    u16*   Wobf = (u16*)(ws + 58320896);
    u16*   Kp   = (u16*)(ws + 60817408);
    u16*   VpT  = (u16*)(ws + 77594624);
    float* S    = (float*)(ws);
    u16*   P    = (u16*)(ws + 35254272);
    u16*   Ctx  = Kp;

    const float inv_sqrt_d = 0.03125f;   // 1/sqrt(1024)

    // ---- one batched cast launch for all six fp32->bf16 tensors
    CastDesc cd;
    cd.src[0] = K;  cd.dst[0] = Kbf;
    cd.src[1] = V;  cd.dst[1] = Vbf;
    cd.src[2] = Q;  cd.dst[2] = Qbf;
    cd.src[3] = Wk; cd.dst[3] = Wkbf;
    cd.src[4] = Wv; cd.dst[4] = Wvbf;
    cd.src[5] = Wo; cd.dst[5] = Wobf;
    long acc = 0;
    const long sizes[6] = {(long)BB*LK*D2, (long)BB*LK*D2, (long)BB*LQ*D1,
                           (long)D1*D2, (long)D1*D2, (long)D1*D1};
    for (int i = 0; i < 6; ++i) { acc += sizes[i] / 4; cd.end[i] = acc; }
    cast6_kernel<<<dim3((unsigned)((acc + 255) / 256)), 256, 0, stream>>>(cd, acc);

    // ---- K projection: Kp[b][k][d] = K @ Wk^T + bk  (row-major epi -> fold OK)
    mm_bf16<128, EPI_BF16_BIAS><<<dim3(D1/128, (BB*LK)/128, 1), 256, 0, stream>>>(
        Kbf, Wkbf, Kp, bk, D2, D2, D2, D1, 0, 0, 0, 1.0f);

    // ---- V projection (transposed out): VpT[b][d][k]
    // MUST be z-batched (transposed epilogue; see kernel comment).
    mm_bf16<128, EPI_BF16_T_BIAS><<<dim3(D1/128, LK/128, BB), 256, 0, stream>>>(
        Vbf, Wvbf, VpT, bv, D2, D2, D2, LK,
        (long)LK*D2, 0, (long)D1*LK, 1.0f);

    // ---- scores: S[b][q][k] = (Q @ Kp^T) / 32   (fp32 out, z-batched)
    mm_bf16<128, EPI_F32_SCALE><<<dim3(LK/128, LQ/128, BB), 256, 0, stream>>>(
        Qbf, Kp, S, nullptr, D1, D1, D1, LK,
        (long)LQ*D1, (long)LK*D1, (long)LQ*LK, inv_sqrt_d);

    // ---- softmax rows -> bf16 probs P
    softmax_kernel<<<dim3(BB*LQ), 256, 0, stream>>>(S, P);

    // ---- context: Ctx[b][q][d] = P @ VpT^T   (BN=64, z-batched)
    mm_bf16<64, EPI_BF16><<<dim3(D1/64, LQ/128, BB), 256, 0, stream>>>(
        P, VpT, Ctx, nullptr, LK, LK, LK, D1,
        (long)LQ*LK, (long)D1*LK, (long)LQ*D1, 1.0f);

    // ---- output: out = Ctx @ Wo^T + bo  (fp32, BN=64, row-major -> fold OK)
    mm_bf16<64, EPI_F32_BIAS><<<dim3(D1/64, (BB*LQ)/128, 1), 256, 0, stream>>>(
        Ctx, Wobf, out, bo, D1, D1, D1, D1, 0, 0, 0, 1.0f);
}